// Round 1
// baseline (14198.364 us; speedup 1.0000x reference)
//
#include <hip/hip_runtime.h>
#include <hip/hip_bf16.h>

// Problem constants
#define BB 32
#define CC 256
#define HH 56
#define WW 56
#define OO 512
#define KK 3
#define CKK (CC * KK * KK)   // 2304
#define NW  (CKK * OO)       // 1179648 weights

// ---------------------------------------------------------------------------
// Detect whether the bool mask arrays arrived as 1-byte bools or int32.
// If uint8-packed, reading them as u32 words yields values > 1 almost surely
// within the first 16384 words (64 KB). If int32, every word is 0 or 1.
// Writes flag (1 = byte bools, 0 = int32 bools) to *flag.
// ---------------------------------------------------------------------------
__global__ void detect_bool_width(const unsigned int* __restrict__ pos,
                                  unsigned int* __restrict__ flag) {
    unsigned int v = 0;
    for (int i = threadIdx.x; i < 16384; i += 256) v |= pos[i];
    __shared__ unsigned int red;
    if (threadIdx.x == 0) red = 0u;
    __syncthreads();
    if (v > 1u) atomicOr(&red, 1u);
    __syncthreads();
    if (threadIdx.x == 0) *flag = red;
}

// ---------------------------------------------------------------------------
// Decode ternary weight: w[ckk*O + o] = pos - neg  in {-1, 0, +1}  (fp32)
// ---------------------------------------------------------------------------
__global__ void decode_weights(const void* __restrict__ posv,
                               const void* __restrict__ negv,
                               const unsigned int* __restrict__ flag,
                               float* __restrict__ w) {
    int i = blockIdx.x * 256 + threadIdx.x;
    if (i >= NW) return;
    int p, q;
    if (*flag) {  // 1-byte bools
        p = ((const unsigned char*)posv)[i];
        q = ((const unsigned char*)negv)[i];
    } else {      // int32 bools
        p = ((const int*)posv)[i];
        q = ((const int*)negv)[i];
    }
    w[i] = (float)(p - q);
}

// ---------------------------------------------------------------------------
// Direct conv. Each thread computes 8 consecutive output channels at one
// (b, y, x). Weight loads (2x float4) are wave-uniform (broadcast); x loads
// are coalesced along sp. Grid: 32 b * 64 o-groups * 3136 sp / 256.
// ---------------------------------------------------------------------------
__global__ __launch_bounds__(256) void conv_ternary(
    const float* __restrict__ x,
    const float* __restrict__ w,
    float* __restrict__ out) {
    int tid  = blockIdx.x * 256 + threadIdx.x;
    int sp   = tid % (HH * WW);
    int rest = tid / (HH * WW);     // b*64 + og
    int og   = rest & 63;
    int b    = rest >> 6;
    int y    = sp / WW;
    int x0   = sp - y * WW;

    const float* xb = x + (size_t)b * CC * HH * WW;
    const float* wp = w + og * 8;

    float acc[8];
#pragma unroll
    for (int j = 0; j < 8; ++j) acc[j] = 0.f;

    for (int c = 0; c < CC; ++c) {
        const float* xc = xb + c * HH * WW;
        int ckk_c = c * 9;
#pragma unroll
        for (int kh = 0; kh < KK; ++kh) {
            int yy = y + kh - 1;
            if ((unsigned)yy >= HH) continue;
            const float* xr = xc + yy * WW;
#pragma unroll
            for (int kw = 0; kw < KK; ++kw) {
                int xx = x0 + kw - 1;
                if ((unsigned)xx >= WW) continue;
                float xv = xr[xx];
                const float4* wv =
                    (const float4*)(wp + (ckk_c + kh * 3 + kw) * OO);
                float4 w0 = wv[0];
                float4 w1 = wv[1];
                acc[0] += w0.x * xv;
                acc[1] += w0.y * xv;
                acc[2] += w0.z * xv;
                acc[3] += w0.w * xv;
                acc[4] += w1.x * xv;
                acc[5] += w1.y * xv;
                acc[6] += w1.z * xv;
                acc[7] += w1.w * xv;
            }
        }
    }

    float* op = out + ((size_t)b * OO + og * 8) * (HH * WW) + sp;
#pragma unroll
    for (int j = 0; j < 8; ++j) op[(size_t)j * (HH * WW)] = acc[j];
}

extern "C" void kernel_launch(void* const* d_in, const int* in_sizes, int n_in,
                              void* d_out, int out_size, void* d_ws, size_t ws_size,
                              hipStream_t stream) {
    const float* x   = (const float*)d_in[0];
    const void*  pos = d_in[1];
    const void*  neg = d_in[2];
    float* out = (float*)d_out;

    // ws layout: [0..3] detection flag, [256..] decoded fp32 weights (4.71 MB)
    unsigned int* flag = (unsigned int*)d_ws;
    float* w = (float*)((char*)d_ws + 256);

    detect_bool_width<<<1, 256, 0, stream>>>((const unsigned int*)pos, flag);
    decode_weights<<<(NW + 255) / 256, 256, 0, stream>>>(pos, neg, flag, w);

    int total = BB * 64 * (HH * WW);   // 6,422,528 threads
    conv_ternary<<<total / 256, 256, 0, stream>>>(x, w, out);
}

// Round 2
// 759.541 us; speedup vs baseline: 18.6934x; 18.6934x over previous
//
#include <hip/hip_runtime.h>
#include <hip/hip_bf16.h>

#define BB 32
#define CC 256
#define HH 56
#define WW 56
#define OO 512
#define CKK 2304          // 256*9

// padded x: [b][c][58 rows][64 cols] bf16
#define PROWS 58
#define PPITCH 64
#define PSLICE (PROWS * PPITCH)   // 3712 elems per (b,c) plane

// GEMM tiling
#define NY 4
#define NX 28
#define NTILE 112         // NY * NX
#define BPITCH 40         // shorts per n-row in LDS (80 B: aligned + 2-way-free banks)

typedef __bf16 bf16x8 __attribute__((ext_vector_type(8)));
typedef float  f32x4  __attribute__((ext_vector_type(4)));
typedef unsigned short u16x8 __attribute__((ext_vector_type(8)));

// ws layout
#define WT_OFF 4096                                   // bf16 weights [o][k'], 2.36 MB
#define XP_OFF (WT_OFF + (size_t)OO * CKK * 2)        // padded bf16 x, 60.8 MB

// ---------------------------------------------------------------------------
// Detect 1-byte vs 4-byte bools (u32 words > 1 => byte bools).
// ---------------------------------------------------------------------------
__global__ void detect_bool_width(const unsigned int* __restrict__ pos,
                                  unsigned int* __restrict__ flag) {
    unsigned int v = 0;
    for (int i = threadIdx.x; i < 16384; i += 256) v |= pos[i];
    __shared__ unsigned int red;
    if (threadIdx.x == 0) red = 0u;
    __syncthreads();
    if (v > 1u) atomicOr(&red, 1u);
    __syncthreads();
    if (threadIdx.x == 0) *flag = red;
}

// ---------------------------------------------------------------------------
// Decode ternary weights to bf16 bits, transposed to w[o][k'] with
// k' = (kh*3+kw)*256 + c. LDS transpose keeps both sides coalesced.
// Grid: 288 blocks = 8 o-tiles * 9 khw * 4 c-tiles, 256 threads.
// ---------------------------------------------------------------------------
__global__ __launch_bounds__(256) void decode_w(
    const void* __restrict__ posv, const void* __restrict__ negv,
    const unsigned int* __restrict__ flag,
    unsigned short* __restrict__ wt) {
    __shared__ unsigned short lds[64][65];
    int blk = blockIdx.x;
    int ot  = blk & 7;
    int khw = (blk >> 3) % 9;
    int ct  = blk / 72;
    int o0 = ot * 64, c0 = ct * 64;
    int t = threadIdx.x;
    int o_l = t & 63, row4 = t >> 6;
    bool bytes = (*flag != 0u);
#pragma unroll
    for (int r = 0; r < 16; ++r) {
        int c_l = row4 + r * 4;
        long k = (long)(c0 + c_l) * 9 + khw;     // input k = c*9 + kh*3 + kw
        long idx = k * OO + o0 + o_l;
        int p, q;
        if (bytes) { p = ((const unsigned char*)posv)[idx];
                     q = ((const unsigned char*)negv)[idx]; }
        else       { p = ((const int*)posv)[idx];
                     q = ((const int*)negv)[idx]; }
        lds[c_l][o_l] = p ? 0x3F80u : (q ? 0xBF80u : 0u);  // bf16 +1/-1/0
    }
    __syncthreads();
#pragma unroll
    for (int r = 0; r < 16; ++r) {
        int o_r = row4 + r * 4;
        int kcol = t & 63;
        wt[(size_t)(o0 + o_r) * CKK + khw * 256 + c0 + kcol] = lds[kcol][o_r];
    }
}

// ---------------------------------------------------------------------------
// Pad + convert x to bf16: x_pad[b][c][58][64], 1-elem zero border.
// One block per (b,c) plane.
// ---------------------------------------------------------------------------
__global__ __launch_bounds__(256) void pad_x(const float* __restrict__ x,
                                             unsigned short* __restrict__ xp) {
    int bc = blockIdx.x;                          // 8192
    const float* xs = x + (size_t)bc * (HH * WW);
    unsigned short* xd = xp + (size_t)bc * PSLICE;
    for (int i = threadIdx.x; i < PSLICE; i += 256) {
        int xx = i & 63, yy = i >> 6;
        float v = 0.f;
        if (yy >= 1 && yy <= HH && xx >= 1 && xx <= WW)
            v = xs[(yy - 1) * WW + xx - 1];
        __hip_bfloat16 h = __float2bfloat16(v);
        xd[i] = *(unsigned short*)&h;
    }
}

// ---------------------------------------------------------------------------
// Implicit-GEMM conv via bf16 MFMA.
//   M tile 256 (o), N tile 112 (4 y-rows x 28 x-cols), K step 32 (c-chunk).
//   4 waves split M (64 o each); A-frags direct from global (L2-resident);
//   B (x-patches) transposed into LDS [n][k] each K-step.
// Grid: (896 n-blocks, 2 m-blocks), 256 threads.
// ---------------------------------------------------------------------------
__global__ __launch_bounds__(256, 2) void conv_mfma(
    const unsigned short* __restrict__ xp,
    const unsigned short* __restrict__ wt,
    float* __restrict__ out) {
    __shared__ __align__(16) unsigned short Bs[NTILE * BPITCH];  // 8960 B

    int t = threadIdx.x;
    int w = t >> 6, lane = t & 63, lm = lane & 15, lq = lane >> 4;

    int gn = blockIdx.x;                 // 896 = 32 b * 14 yt * 2 xt
    int obase = blockIdx.y << 8;
    int b = gn / 28;
    int rem = gn - b * 28;
    int y0 = (rem >> 1) * NY;
    int x0 = (rem & 1) * NX;

    // B-staging constants: thread t<224 handles n = t%112, c-halfchunk = t/112
    int sn = t % NTILE;
    int ch = t / NTILE;
    bool active = (t < 2 * NTILE);
    int ny = sn / NX, nx = sn - (sn / NX) * NX;
    const unsigned short* xbase =
        xp + (size_t)(b * CC) * PSLICE + (y0 + ny) * PPITCH + (x0 + nx);
    int woff = sn * BPITCH + ch * 16;

    // A-frag base: o = obase + w*64 + mt*16 + lm ; k = s*32 + lq*8
    const unsigned short* abase =
        wt + (size_t)(obase + w * 64 + lm) * CKK + lq * 8;

    f32x4 acc[4][7];
#pragma unroll
    for (int i = 0; i < 4; ++i)
#pragma unroll
        for (int j = 0; j < 7; ++j) acc[i][j] = (f32x4){0.f, 0.f, 0.f, 0.f};

    for (int s = 0; s < 72; ++s) {
        int khw = s >> 3;
        int kh = khw / 3, kw = khw - kh * 3;
        int c0 = (s & 7) << 5;

        __syncthreads();
        if (active) {
            const unsigned short* src =
                xbase + (size_t)(c0 + ch * 16) * PSLICE + kh * PPITCH + kw;
            u16x8 v0, v1;
#pragma unroll
            for (int j = 0; j < 8; ++j) v0[j] = src[j * PSLICE];
#pragma unroll
            for (int j = 0; j < 8; ++j) v1[j] = src[(j + 8) * PSLICE];
            *(u16x8*)&Bs[woff] = v0;
            *(u16x8*)&Bs[woff + 8] = v1;
        }
        __syncthreads();

        bf16x8 af[4];
#pragma unroll
        for (int mt = 0; mt < 4; ++mt)
            af[mt] = *(const bf16x8*)(abase + (size_t)mt * 16 * CKK + s * 32);

#pragma unroll
        for (int nt = 0; nt < 7; ++nt) {
            bf16x8 bfr = *(const bf16x8*)&Bs[(nt * 16 + lm) * BPITCH + lq * 8];
#pragma unroll
            for (int mt = 0; mt < 4; ++mt)
                acc[mt][nt] = __builtin_amdgcn_mfma_f32_16x16x32_bf16(
                    af[mt], bfr, acc[mt][nt], 0, 0, 0);
        }
    }

    // Epilogue: D row = (lane>>4)*4 + r (o), col = lane&15 (n)
    int orow0 = obase + w * 64 + lq * 4;
#pragma unroll
    for (int mt = 0; mt < 4; ++mt) {
#pragma unroll
        for (int nt = 0; nt < 7; ++nt) {
            int nl = nt * 16 + lm;
            int nyy = nl / NX, nxx = nl - nyy * NX;
            size_t base =
                ((size_t)(b * OO + orow0 + mt * 16) * HH + (y0 + nyy)) * WW +
                (x0 + nxx);
#pragma unroll
            for (int r = 0; r < 4; ++r)
                out[base + (size_t)r * HH * WW] = acc[mt][nt][r];
        }
    }
}

extern "C" void kernel_launch(void* const* d_in, const int* in_sizes, int n_in,
                              void* d_out, int out_size, void* d_ws, size_t ws_size,
                              hipStream_t stream) {
    const float* x   = (const float*)d_in[0];
    const void*  pos = d_in[1];
    const void*  neg = d_in[2];
    float* out = (float*)d_out;

    unsigned int* flag = (unsigned int*)d_ws;
    unsigned short* wt = (unsigned short*)((char*)d_ws + WT_OFF);
    unsigned short* xpad = (unsigned short*)((char*)d_ws + XP_OFF);

    detect_bool_width<<<1, 256, 0, stream>>>((const unsigned int*)pos, flag);
    decode_w<<<288, 256, 0, stream>>>(pos, neg, flag, wt);
    pad_x<<<BB * CC, 256, 0, stream>>>(x, xpad);
    conv_mfma<<<dim3(896, 2), 256, 0, stream>>>(xpad, wt, out);
}

// Round 3
// 616.294 us; speedup vs baseline: 23.0383x; 1.2324x over previous
//
#include <hip/hip_runtime.h>
#include <hip/hip_bf16.h>

#define BB 32
#define CC 256
#define HH 56
#define WW 56
#define OO 512
#define CKK 2304

// padded x, NHWC bf16: [b][pix = y*58 + x][c], y,x in [0,58)
#define XR 58
#define XC 58
#define XPIX (XR * XC)        // 3364

// GEMM tiling: M-tile 256 (o), N-tile 112 = 4 y-rows x 28 x-cols
#define NY 4
#define NX 28
#define NTILE 112
#define TPC 30                // tile pixel cols (NX+2)
#define TPIX 180              // 6 rows * 30 cols
#define BUFB 16384            // LDS buffer stride (bytes); used 11,520

typedef __bf16 bf16x8 __attribute__((ext_vector_type(8)));
typedef float  f32x4  __attribute__((ext_vector_type(4)));

#define WT_OFF 4096
#define XP_OFF (WT_OFF + (size_t)OO * CKK * 2)   // 2.36 MB of weights

// ---------------------------------------------------------------------------
// Detect 1-byte vs 4-byte bools (u32 words > 1 => byte bools).
// ---------------------------------------------------------------------------
__global__ void detect_bool_width(const unsigned int* __restrict__ pos,
                                  unsigned int* __restrict__ flag) {
    unsigned int v = 0;
    for (int i = threadIdx.x; i < 16384; i += 256) v |= pos[i];
    __shared__ unsigned int red;
    if (threadIdx.x == 0) red = 0u;
    __syncthreads();
    if (v > 1u) atomicOr(&red, 1u);
    __syncthreads();
    if (threadIdx.x == 0) *flag = red;
}

// ---------------------------------------------------------------------------
// Decode ternary weights to bf16, transposed to w[o][k'] with
// k' = (c>>5)*288 + (kh*3+kw)*32 + (c&31)  (c-chunk-major, khw, c-in-chunk).
// ---------------------------------------------------------------------------
__global__ __launch_bounds__(256) void decode_w(
    const void* __restrict__ posv, const void* __restrict__ negv,
    const unsigned int* __restrict__ flag,
    unsigned short* __restrict__ wt) {
    __shared__ unsigned short lds[64][65];
    int blk = blockIdx.x;
    int ot  = blk & 7;
    int khw = (blk >> 3) % 9;
    int ct  = blk / 72;
    int o0 = ot * 64, c0 = ct * 64;
    int t = threadIdx.x;
    int o_l = t & 63, row4 = t >> 6;
    bool bytes = (*flag != 0u);
#pragma unroll
    for (int r = 0; r < 16; ++r) {
        int c_l = row4 + r * 4;
        long k = (long)(c0 + c_l) * 9 + khw;     // input k = c*9 + kh*3 + kw
        long idx = k * OO + o0 + o_l;
        int p, q;
        if (bytes) { p = ((const unsigned char*)posv)[idx];
                     q = ((const unsigned char*)negv)[idx]; }
        else       { p = ((const int*)posv)[idx];
                     q = ((const int*)negv)[idx]; }
        lds[c_l][o_l] = p ? 0x3F80u : (q ? 0xBF80u : 0u);
    }
    __syncthreads();
#pragma unroll
    for (int r = 0; r < 16; ++r) {
        int o_r = row4 + r * 4;
        int c = c0 + (t & 63);
        wt[(size_t)(o0 + o_r) * CKK + (c >> 5) * 288 + khw * 32 + (c & 31)] =
            lds[t & 63][o_r];
    }
}

// ---------------------------------------------------------------------------
// Pad + convert + transpose x to NHWC bf16: xp[b][y*58+x][c].
// One block per (b, y) output row; LDS transpose per 64-c chunk.
// ---------------------------------------------------------------------------
__global__ __launch_bounds__(256) void pad_x(const float* __restrict__ x,
                                             unsigned short* __restrict__ xp) {
    int blk = blockIdx.x;                 // 32*58
    int b = blk / XR, y = blk - b * XR;
    int t = threadIdx.x;
    unsigned short* rowp = xp + ((size_t)b * XPIX + (size_t)y * XC) * CC;
    if (y == 0 || y == XR - 1) {
        uint4 z = {0, 0, 0, 0};
        for (int i = t; i < XC * CC / 8; i += 256) ((uint4*)rowp)[i] = z;
        return;
    }
    __shared__ float lds[WW][65];
    for (int cb = 0; cb < 4; ++cb) {
        if (cb) __syncthreads();
#pragma unroll
        for (int i = 0; i < 14; ++i) {    // 3584 = 64 c * 56 x
            int idx = i * 256 + t;
            int cl = idx / WW, xx = idx - cl * WW;
            lds[xx][cl] =
                x[(((size_t)b * CC + cb * 64 + cl) * HH + (y - 1)) * WW + xx];
        }
        __syncthreads();
#pragma unroll
        for (int i = 0; i < 15; ++i) {    // 3712 = 58 x * 64 c
            int idx = i * 256 + t;
            if (idx < XC * 64) {
                int xx = idx >> 6, cl = idx & 63;
                float v = (xx == 0 || xx == XC - 1) ? 0.f : lds[xx - 1][cl];
                __hip_bfloat16 h = __float2bfloat16(v);
                rowp[(size_t)xx * CC + cb * 64 + cl] = *(unsigned short*)&h;
            }
        }
    }
}

// ---------------------------------------------------------------------------
// Implicit-GEMM conv, bf16 MFMA, c-chunk-outer K-loop.
//   Per chunk: stage 180 pix x 32 c tile via global_load_lds (double-buffered),
//   then 9 khw K-steps x 28 MFMAs per wave from LDS. 1 barrier / chunk.
// Grid 1792 = 896 n-blocks x 2 m-blocks (m swizzled onto same XCD).
// ---------------------------------------------------------------------------
__global__ __launch_bounds__(256, 2) void conv_mfma(
    const unsigned short* __restrict__ xp,
    const unsigned short* __restrict__ wt,
    float* __restrict__ out) {
    __shared__ __align__(1024) unsigned short Bs[2 * BUFB / 2];

    int t = threadIdx.x;
    int w = t >> 6, lane = t & 63, lm = lane & 15, lq = lane >> 4;

    int bx = blockIdx.x;
    int mb = (bx >> 3) & 1;                       // m innermost on same XCD
    int gn = ((bx >> 4) << 3) | (bx & 7);         // 0..895
    int b = gn / 28;
    int rem = gn - b * 28;
    int y0 = (rem >> 1) << 2;                     // 0..52
    int x0 = (rem & 1) * NX;                      // 0 or 28

    // B-fragment LDS byte offsets per nt (kh=kw=0 position)
    int bofs[7];
#pragma unroll
    for (int nt = 0; nt < 7; ++nt) {
        int n = nt * 16 + lm;
        int ny = n / NX, nx = n - (n / NX) * NX;
        bofs[nt] = (ny * TPC + nx) * 64 + lq * 16;
    }

    // Staging: 720 16-B units; 3 segments/wave, u = (w*3+i)*64 + lane
    const unsigned short* gsrc[3];
    int useg[3];
#pragma unroll
    for (int i = 0; i < 3; ++i) {
        int u = (w * 3 + i) * 64 + lane;
        useg[i] = u;
        int pix = u >> 2, quad = u & 3;
        int py = pix / TPC, px = pix - py * TPC;
        gsrc[i] = xp + ((size_t)b * XPIX + (y0 + py) * XC + (x0 + px)) * CC +
                  quad * 8;
    }
    int ldsseg = (w * 3) * 1024;

    const unsigned short* aptr[4];
#pragma unroll
    for (int mt = 0; mt < 4; ++mt)
        aptr[mt] = wt + (size_t)(mb * 256 + w * 64 + mt * 16 + lm) * CKK + lq * 8;

    f32x4 acc[4][7];
#pragma unroll
    for (int i = 0; i < 4; ++i)
#pragma unroll
        for (int j = 0; j < 7; ++j) acc[i][j] = (f32x4){0.f, 0.f, 0.f, 0.f};

    bf16x8 af[12];

#define STAGE(CHOFF, POFS)                                                     \
    {                                                                          \
        _Pragma("unroll") for (int i = 0; i < 3; ++i) {                        \
            if (useg[i] < TPIX * 4)                                            \
                __builtin_amdgcn_global_load_lds(                              \
                    (const __attribute__((address_space(1))) void*)(gsrc[i] +  \
                                                                    (CHOFF)),  \
                    (__attribute__((address_space(3))) void*)((char*)Bs +      \
                                                              (POFS) + ldsseg +\
                                                              i * 1024),       \
                    16, 0, 0);                                                 \
        }                                                                      \
    }

#define LOADA(CHEL, G)                                                         \
    {                                                                          \
        _Pragma("unroll") for (int j = 0; j < 3; ++j)                          \
            _Pragma("unroll") for (int mt = 0; mt < 4; ++mt)                   \
                af[j * 4 + mt] = *(const bf16x8*)(aptr[mt] + (CHEL) +          \
                                                  ((G) * 3 + j) * 32);         \
    }

#define GRP(G, POFS)                                                           \
    {                                                                          \
        _Pragma("unroll") for (int j = 0; j < 3; ++j) {                        \
            const int khw = (G) * 3 + j;                                       \
            const int kh = khw / 3, kw = khw - kh * 3;                         \
            _Pragma("unroll") for (int nt = 0; nt < 7; ++nt) {                 \
                bf16x8 bfr = *(const bf16x8*)((char*)Bs + (POFS) +             \
                                              (kh * TPC + kw) * 64 + bofs[nt]);\
                _Pragma("unroll") for (int mt = 0; mt < 4; ++mt)               \
                    acc[mt][nt] = __builtin_amdgcn_mfma_f32_16x16x32_bf16(     \
                        af[j * 4 + mt], bfr, acc[mt][nt], 0, 0, 0);            \
            }                                                                  \
        }                                                                      \
    }

    STAGE(0, 0);                 // chunk 0 -> buf0
    LOADA(0, 0);                 // chunk 0, khw 0-2
    for (int it = 0; it < 4; ++it) {
        // ---- chunk 2*it (buf0) ----
        __syncthreads();         // drains staging of this chunk
        STAGE(32, BUFB);         // chunk 2it+1 -> buf1 (hidden behind compute)
        GRP(0, 0);
        LOADA(0, 1);  GRP(1, 0);
        LOADA(0, 2);  GRP(2, 0);
        LOADA(288, 0);           // next chunk's khw 0-2 (pre-barrier)
        // ---- chunk 2*it+1 (buf1) ----
        __syncthreads();
        if (it < 3) STAGE(64, 0);        // chunk 2it+2 -> buf0
        GRP(0, BUFB);
        LOADA(288, 1); GRP(1, BUFB);
        LOADA(288, 2); GRP(2, BUFB);
        if (it < 3) {
#pragma unroll
            for (int mt = 0; mt < 4; ++mt) aptr[mt] += 576;
#pragma unroll
            for (int i = 0; i < 3; ++i) gsrc[i] += 64;
            LOADA(0, 0);                 // chunk 2it+2, khw 0-2
        }
    }
#undef STAGE
#undef LOADA
#undef GRP

    // Epilogue: D row = lq*4 + r (o), col = lm (n)
#pragma unroll
    for (int mt = 0; mt < 4; ++mt) {
        int o = mb * 256 + w * 64 + mt * 16 + lq * 4;
#pragma unroll
        for (int nt = 0; nt < 7; ++nt) {
            int n = nt * 16 + lm;
            int ny = n / NX, nx = n - (n / NX) * NX;
            size_t base =
                (((size_t)b * OO + o) * HH + (y0 + ny)) * WW + (x0 + nx);
#pragma unroll
            for (int r = 0; r < 4; ++r)
                out[base + (size_t)r * HH * WW] = acc[mt][nt][r];
        }
    }
}

extern "C" void kernel_launch(void* const* d_in, const int* in_sizes, int n_in,
                              void* d_out, int out_size, void* d_ws, size_t ws_size,
                              hipStream_t stream) {
    const float* x   = (const float*)d_in[0];
    const void*  pos = d_in[1];
    const void*  neg = d_in[2];
    float* out = (float*)d_out;

    unsigned int* flag = (unsigned int*)d_ws;
    unsigned short* wt = (unsigned short*)((char*)d_ws + WT_OFF);
    unsigned short* xpad = (unsigned short*)((char*)d_ws + XP_OFF);

    detect_bool_width<<<1, 256, 0, stream>>>((const unsigned int*)pos, flag);
    decode_w<<<288, 256, 0, stream>>>(pos, neg, flag, wt);
    pad_x<<<BB * XR, 256, 0, stream>>>(x, xpad);
    conv_mfma<<<dim3(1792), 256, 0, stream>>>(xpad, wt, out);
}